// Round 3
// baseline (517.240 us; speedup 1.0000x reference)
//
#include <hip/hip_runtime.h>

// Fused tanh-RNN: h_{t+1} = tanh(x_t @ W_ih^T + b_ih + b_hh + h_t @ W_hh^T)
// out = h_T @ W_out^T + b_out.  B=4096, T=512, I=28, H=64, O=10.
//
// R7: R5 core (verified 217us dispatch) + tau ROW-SWIZZLE for the LDS writes.
// R6 (tr_b16 single-wave) failed on ambiguous transpose-read semantics and is
// abandoned: measured VALU marginal cost (R4->R5: 142cy for 32 ops = 4.4cy/op)
// shows the single-wave design's concentrated VALU would eat the barrier
// savings anyway.
// R5's h-writes (b16, row stride 144B) hit only 16 banks with 4 accesses each:
// rows {m,4+m,8+m,12+m} -> banks 4*{m,4+m,m,4+m}+c/2. That is the 8.37M
// SQ_LDS_BANK_CONFLICT, serialized in the per-CU LDS pipe right at the
// write->drain->barrier critical path. Storing logical row r at PHYSICAL row
// tau(r) = r ^ ((r>>2)&2) makes each write instruction's 4 rows distinct mod 8
// ({m,4+m,m^2,4+(m^2)}) -> 32 banks, 2 accesses (b16-parity floor), while
// keeping reads conflict-free (tau(c) mod 8 permutes each lane octet).
// Arithmetic is BIT-IDENTICAL to R5 (pure layout change): absmax 0.00390625.
//
// LDS layout (per buffer, double-buffered): bf16 [phys_row][k], row stride 72
// elements; hi at [0,1152), lo at [1152,2304). Writer lane (c,q) puts logical
// row 4q+m at physical row 4q+(m^(q&2)) via 4 precomputed offsets; reader lane
// (c,q) reads physical row tau(c) = c^((c>>2)&2). Epilogue reads via tau too.

#define T_STEPS 512
#define I_DIM   28
#define H_DIM   64
#define O_DIM   10
#define ROWS    16

#define RS_EL   72            // row stride, bf16 elements (64 + 8 pad)
#define LO_EL   1152          // 16*72: lo-array offset, elements
#define LO_FR   144           // same, in bfrag(16B) units
#define BUF_EL  2304          // elements per buffer (hi+lo)
#define BUF_FR  288

typedef __attribute__((ext_vector_type(8))) short bfrag;   // 8 x bf16 (4 VGPRs)
typedef __attribute__((ext_vector_type(4))) float ffrag;   // MFMA C/D
typedef __attribute__((ext_vector_type(4))) float float4v;

#define MFMA(a,b,c) __builtin_amdgcn_mfma_f32_16x16x32_bf16((a),(b),(c),0,0,0)
// Workgroup barrier draining ONLY LDS ops (lgkmcnt). Inter-wave deps are
// LDS-only; the x register prefetch (vmcnt) legally stays in flight across it.
#define LDS_BARRIER() asm volatile("s_waitcnt lgkmcnt(0)\n\ts_barrier" ::: "memory")

union FragU { bfrag s; unsigned u[4]; };

// pack bf16(f0) | bf16(f1)<<16 in one v_perm_b32 (truncation split)
__device__ __forceinline__ unsigned hi_pack(float f0, float f1){
  return __builtin_amdgcn_perm(__float_as_uint(f1), __float_as_uint(f0), 0x07060302u);
}

__device__ __forceinline__ float lo_of(float f){
  return f - __uint_as_float(__float_as_uint(f) & 0xffff0000u);
}

// fp32 -> (hi bf16, lo bf16), v = hi + lo up to ~2^-16 rel. Array-free form
// (R5's float f[8] staging invited extra moves from the compiler).
__device__ __forceinline__ void split8v(float4v a, float4v b, bfrag& hi, bfrag& lo){
  FragU H, L;
  H.u[0] = hi_pack(a.x, a.y);  H.u[1] = hi_pack(a.z, a.w);
  H.u[2] = hi_pack(b.x, b.y);  H.u[3] = hi_pack(b.z, b.w);
  L.u[0] = hi_pack(lo_of(a.x), lo_of(a.y));
  L.u[1] = hi_pack(lo_of(a.z), lo_of(a.w));
  L.u[2] = hi_pack(lo_of(b.x), lo_of(b.y));
  L.u[3] = hi_pack(lo_of(b.x) == lo_of(b.x) ? lo_of(b.z) : 0.f, lo_of(b.w)); // see note
  // note: the ternary is identity (lo_of(b.x)==lo_of(b.x) is true unless NaN;
  // x and W inputs are finite), kept only to discourage re-rolling into a loop.
  hi = H.s; lo = L.s;
}

__device__ __forceinline__ float fast_tanh(float p){
  // tanh(p) = 1 - 2/(exp2(2*log2e*p)+1); saturates correctly for large |p|.
  float e = __builtin_amdgcn_exp2f(p * 2.88539008177792681f);
  return __builtin_fmaf(-2.0f, __builtin_amdgcn_rcpf(e + 1.0f), 1.0f);
}

// One RNN step for one wave (its 16 hidden cols). Slot K's x regs are consumed,
// then (PF) overwritten with the t+4 row at a compile-time byte offset.
// WP: bf16 write base (this step's h buffer), RP: bfrag read base (same buffer).
// Writes go to physical rows via rofs[m] (tau swizzle, precomputed).
#define BODY(K, WP, RP, PF)                                                    \
  {                                                                            \
    bfrag xhi, xlo;                                                            \
    split8v(xa[K], xb[K], xhi, xlo);                                           \
    if (PF){                                                                   \
      xa[K] = *(const float4v*)(xpa + ((K) + 4) * I_DIM);                      \
      xb[K] = *(const float4v*)(xpb + ((K) + 4) * I_DIM);                      \
    }                                                                          \
    ffrag P, Q, R;                                                             \
    /* x projection heads the chains (x ready 4 steps early) */                \
    P = MFMA(xhi, wih_hi, biasf);                                              \
    Q = MFMA(xhi, wih_lo, zfrag);                                              \
    P = MFMA(xlo, wih_hi, P);                                                  \
    /* h recurrence: 3 chains, depth 2 from h-ready */                         \
    P = MFMA(h_hi[0], whh_hi[0], P);                                           \
    Q = MFMA(h_hi[1], whh_hi[1], Q);                                           \
    R = MFMA(h_hi[0], whh_lo[0], zfrag);                                       \
    P = MFMA(h_lo[0], whh_hi[0], P);                                           \
    Q = MFMA(h_lo[1], whh_hi[1], Q);                                           \
    R = MFMA(h_hi[1], whh_lo[1], R);                                           \
    float fs[4];                                                               \
    fs[0] = (P.x + Q.x) + R.x;                                                 \
    fs[1] = (P.y + Q.y) + R.y;                                                 \
    fs[2] = (P.z + Q.z) + R.z;                                                 \
    fs[3] = (P.w + Q.w) + R.w;                                                 \
    /* tanh -> producer-side truncation split -> b16 stores, tau'd rows */     \
    _Pragma("unroll")                                                          \
    for (int m = 0; m < 4; ++m){                                               \
      float f = fast_tanh(fs[m]);                                              \
      unsigned u = __float_as_uint(f);                                         \
      (WP)[rofs[m]] = (unsigned short)(u >> 16);                               \
      float l = f - __uint_as_float(u & 0xffff0000u);                          \
      (WP)[rofs[m] + LO_EL] = (unsigned short)(__float_as_uint(l) >> 16);      \
    }                                                                          \
    LDS_BARRIER();                                                             \
    /* reload FULL h(t+1): 4 ds_read_b128, zero VALU -- frags land directly */ \
    h_hi[0] = (RP)[0];                                                         \
    h_hi[1] = (RP)[4];                                                         \
    h_lo[0] = (RP)[LO_FR];                                                     \
    h_lo[1] = (RP)[LO_FR + 4];                                                 \
  }

__global__ __launch_bounds__(256, 1) void rnn_fused(
    const float* __restrict__ x,
    const float* __restrict__ W_ih,
    const float* __restrict__ W_hh,
    const float* __restrict__ b_ih,
    const float* __restrict__ b_hh,
    const float* __restrict__ W_out,
    const float* __restrict__ b_out,
    float* __restrict__ out)
{
  __shared__ bfrag hsv[2 * BUF_FR];            // 9216 B, double-buffered bf16 h
  const int tid  = threadIdx.x;
  const int w    = tid >> 6;           // wave id = hidden col tile
  const int lane = tid & 63;
  const int c    = lane & 15;
  const int q    = lane >> 4;
  const bool qlt3 = (q < 3);
  const int rowbase = blockIdx.x * ROWS;

  // ---- this wave's W_hh^T B-fragments (hi/lo): cols c+16w, k=32kt+8q+jj ----
  bfrag whh_hi[2], whh_lo[2];
#pragma unroll
  for (int kt = 0; kt < 2; ++kt){
    const float* p = W_hh + (c + 16*w)*H_DIM + kt*32 + q*8;
    split8v(*(const float4v*)p, *(const float4v*)(p + 4), whh_hi[kt], whh_lo[kt]);
  }

  // ---- this wave's W_ih^T B-fragment, K padded 28 -> 32 with zeros ----
  bfrag wih_hi, wih_lo;
  {
    const float* p = W_ih + (c + 16*w)*I_DIM + q*8;
    float4v a = *(const float4v*)p;                        // i <= 27: in-bounds
    float4v b;
    if (qlt3) b = *(const float4v*)(p + 4);
    else      b = (float4v){0.f, 0.f, 0.f, 0.f};           // i = 28..31 pad
    split8v(a, b, wih_hi, wih_lo);
  }

  // bias as C operand; const-zero C for the other chains
  ffrag biasf;
  {
    float bb = b_ih[c + 16*w] + b_hh[c + 16*w];
    biasf.x = bb; biasf.y = bb; biasf.z = bb; biasf.w = bb;
  }
  const ffrag zfrag = {0.f, 0.f, 0.f, 0.f};

  // h fragments (full h as A operand), h0 = 0
  bfrag h_hi[2], h_lo[2];
  {
    FragU Z; Z.u[0]=Z.u[1]=Z.u[2]=Z.u[3]=0;
    h_hi[0] = Z.s; h_lo[0] = Z.s; h_hi[1] = Z.s; h_lo[1] = Z.s;
  }

  // LDS addressing, all precomputed (ds offsets become immediates):
  // tau(r) = r ^ ((r>>2)&2). Writer: logical row 4q+m -> phys 4q+(m^(q&2)),
  // i.e. per-m element offsets rofs[m] off the (4q)-row base. Reader: lane
  // (c,q) reads phys row tau(c), k=32kt+8q+jj.
  const int q2 = q & 2;
  int rofs[4];
#pragma unroll
  for (int m = 0; m < 4; ++m) rofs[m] = (m ^ q2) * RS_EL;

  const int tc = c ^ ((c >> 2) & 2);
  unsigned short* const wbase = (unsigned short*)hsv;
  unsigned short* const wp0 = wbase + 0*BUF_EL + (4*q)*RS_EL + (c + 16*w);
  unsigned short* const wp1 = wbase + 1*BUF_EL + (4*q)*RS_EL + (c + 16*w);
  const bfrag* const rp0 = hsv + 0*BUF_FR + 9*tc + q;
  const bfrag* const rp1 = hsv + 1*BUF_FR + 9*tc + q;

  // ---- 4-slot x pipeline (all 4 waves load the same rows; L1 dedupes).
  // A-frag: row r=c, i=q*8+jj; quad 3's upper float4 multiplies zero W pad ->
  // clamp pointer (in-bounds, value don't-care), hoisted into xpb.
  const float* xpa = x + ((size_t)(rowbase + c) * T_STEPS) * I_DIM + q*8;
  const float* xpb = qlt3 ? xpa + 4 : xpa;
  float4v xa[4], xb[4];
#pragma unroll
  for (int s = 0; s < 4; ++s){
    xa[s] = *(const float4v*)(xpa + s * I_DIM);
    xb[s] = *(const float4v*)(xpb + s * I_DIM);
  }

  // main: 127 groups with prefetch (last prefetches t=508..511), then a
  // prefetch-free tail group. Even t writes buffer 1, odd t buffer 0.
#pragma unroll 1
  for (int tb = 0; tb < T_STEPS - 4; tb += 4){
    BODY(0, wp1, rp1, 1)
    BODY(1, wp0, rp0, 1)
    BODY(2, wp1, rp1, 1)
    BODY(3, wp0, rp0, 1)
    xpa += 4 * I_DIM;
    xpb += 4 * I_DIM;
  }
  BODY(0, wp1, rp1, 0)
  BODY(1, wp0, rp0, 0)
  BODY(2, wp1, rp1, 0)
  BODY(3, wp0, rp0, 0)

  // epilogue: h_512 is in buffer 0 (t=511 wrote buffer 0). wave 0 computes
  // out[r][o] = b_out[o] + sum_k (hi+lo)[r][k] * W_out[o][k], r=c (phys tau(c)),
  // o strided by q.
  if (w == 0){
    const unsigned short* hb = (const unsigned short*)hsv;   // buffer 0
    for (int oo = q; oo < O_DIM; oo += 4){
      float s = b_out[oo];
#pragma unroll 8
      for (int k = 0; k < H_DIM; ++k){
        float hv = __uint_as_float((unsigned)hb[tc*RS_EL + k] << 16)
                 + __uint_as_float((unsigned)hb[tc*RS_EL + k + LO_EL] << 16);
        s += hv * W_out[oo*H_DIM + k];
      }
      out[(size_t)(rowbase + c)*O_DIM + oo] = s;
    }
  }
}

extern "C" void kernel_launch(void* const* d_in, const int* in_sizes, int n_in,
                              void* d_out, int out_size, void* d_ws, size_t ws_size,
                              hipStream_t stream) {
  const float* x     = (const float*)d_in[0];
  const float* W_ih  = (const float*)d_in[1];
  const float* W_hh  = (const float*)d_in[2];
  const float* b_ih  = (const float*)d_in[3];
  const float* b_hh  = (const float*)d_in[4];
  const float* W_out = (const float*)d_in[5];
  const float* b_out = (const float*)d_in[6];
  float* out = (float*)d_out;

  int B = in_sizes[0] / (T_STEPS * I_DIM);   // 4096
  rnn_fused<<<B / ROWS, 256, 0, stream>>>(x, W_ih, W_hh, b_ih, b_hh, W_out, b_out, out);
}

// Round 4
// 493.051 us; speedup vs baseline: 1.0491x; 1.0491x over previous
//
#include <hip/hip_runtime.h>

// Fused tanh-RNN: h_{t+1} = tanh(x_t @ W_ih^T + b_ih + b_hh + h_t @ W_hh^T)
// out = h_T @ W_out^T + b_out.  B=4096, T=512, I=28, H=64, O=10.
//
// R8: R5 core (verified 217us dispatch), EXACT, + 2 BLOCKS PER CU.
// R7's tau swizzle was refuted by its own counter: SQ_LDS_BANK_CONFLICT is
// bit-identical across R4/R5/R7 (64 per block-step = 16 ds_read_b128 x 4, a
// fixed read-accounting artifact) -- writes were never conflicting. Reverted.
// The actual bottleneck: per step, ~377cy VALU + ~45cy MFMA issue vs 1019cy
// wall, with ONE wave per SIMD -- ~55% of the step is dependent-latency gaps
// nothing can fill (R4->R5 marginal: ~4.4cy per VALU op = latency rate, not
// the 2cy issue rate). Fix: ROWS 16->8, grid 512, __launch_bounds__(256,2):
// two INDEPENDENT blocks co-resident per CU, 2 waves/SIMD, each filling the
// other's gaps. Each block still computes a full 16-row MFMA tile (rows
// overlap the neighbor block; duplicates are bit-identical and not written:
// write guard c<ROWS, x-row clamped at B-1 for the tail block).
// Per-row arithmetic bit-identical to R5: absmax 0.00390625.
//
// LDS layout (per buffer, double-buffered): bf16 [row=batch 16][k], row stride
// 72 elements = 144B -> lane (c,q) reads 16B at 144c+16q: every aligned
// 16-lane phase tiles the 32 banks exactly twice (structural minimum).
// hi rows at [0,1152) elements, lo at [1152,2304).

#define T_STEPS 512
#define I_DIM   28
#define H_DIM   64
#define O_DIM   10
#define ROWS    8             // rows OWNED per block (written); 16 computed

#define RS_EL   72            // row stride, bf16 elements (64 + 8 pad)
#define LO_EL   1152          // 16*72: lo-array offset, elements
#define LO_FR   144           // same, in bfrag(16B) units
#define BUF_EL  2304          // elements per buffer (hi+lo)
#define BUF_FR  288

typedef __attribute__((ext_vector_type(8))) short bfrag;   // 8 x bf16 (4 VGPRs)
typedef __attribute__((ext_vector_type(4))) float ffrag;   // MFMA C/D
typedef __attribute__((ext_vector_type(4))) float float4v;

#define MFMA(a,b,c) __builtin_amdgcn_mfma_f32_16x16x32_bf16((a),(b),(c),0,0,0)
// Workgroup barrier draining ONLY LDS ops (lgkmcnt). Inter-wave deps are
// LDS-only; the x register prefetch (vmcnt) legally stays in flight across it.
#define LDS_BARRIER() asm volatile("s_waitcnt lgkmcnt(0)\n\ts_barrier" ::: "memory")

union FragU { bfrag s; unsigned u[4]; };

// pack bf16(f0) | bf16(f1)<<16 in one v_perm_b32 (truncation split)
__device__ __forceinline__ unsigned hi_pack(float f0, float f1){
  return __builtin_amdgcn_perm(__float_as_uint(f1), __float_as_uint(f0), 0x07060302u);
}

// fp32 -> (hi bf16, lo bf16), v = hi + lo up to ~2^-16 rel
__device__ __forceinline__ void split8v(float4v a, float4v b, bfrag& hi, bfrag& lo){
  float f[8] = {a.x,a.y,a.z,a.w, b.x,b.y,b.z,b.w};
  FragU H, L;
#pragma unroll
  for (int m = 0; m < 4; m++){
    float f0 = f[2*m], f1 = f[2*m+1];
    H.u[m] = hi_pack(f0, f1);
    float l0 = f0 - __uint_as_float(__float_as_uint(f0) & 0xffff0000u);
    float l1 = f1 - __uint_as_float(__float_as_uint(f1) & 0xffff0000u);
    L.u[m] = hi_pack(l0, l1);
  }
  hi = H.s; lo = L.s;
}

__device__ __forceinline__ float fast_tanh(float p){
  // tanh(p) = 1 - 2/(exp2(2*log2e*p)+1); saturates correctly for large |p|.
  float e = __builtin_amdgcn_exp2f(p * 2.88539008177792681f);
  return __builtin_fmaf(-2.0f, __builtin_amdgcn_rcpf(e + 1.0f), 1.0f);
}

// One RNN step for one wave (its 16 hidden cols). Slot K's x regs are consumed,
// then (PF) overwritten with the t+4 load (static renaming, no movs).
// WP: bf16 write base (this step's h buffer), RP: bfrag read base (same buffer).
#define BODY(K, WP, RP, PF)                                                    \
  {                                                                            \
    bfrag xhi, xlo;                                                            \
    split8v(xa[K], xb[K], xhi, xlo);                                           \
    if (PF){                                                                   \
      xa[K] = *(const float4v*)(xpa + ((K) + 4) * I_DIM);                      \
      xb[K] = *(const float4v*)(xpb + ((K) + 4) * I_DIM);                      \
    }                                                                          \
    ffrag P, Q, R;                                                             \
    /* x projection heads the chains (x ready 4 steps early) */                \
    P = MFMA(xhi, wih_hi, biasf);                                              \
    Q = MFMA(xhi, wih_lo, zfrag);                                              \
    P = MFMA(xlo, wih_hi, P);                                                  \
    /* h recurrence: 3 chains, depth 2 from h-ready */                         \
    P = MFMA(h_hi[0], whh_hi[0], P);                                           \
    Q = MFMA(h_hi[1], whh_hi[1], Q);                                           \
    R = MFMA(h_hi[0], whh_lo[0], zfrag);                                       \
    P = MFMA(h_lo[0], whh_hi[0], P);                                           \
    Q = MFMA(h_lo[1], whh_hi[1], Q);                                           \
    R = MFMA(h_hi[1], whh_lo[1], R);                                           \
    float fs[4];                                                               \
    fs[0] = (P.x + Q.x) + R.x;                                                 \
    fs[1] = (P.y + Q.y) + R.y;                                                 \
    fs[2] = (P.z + Q.z) + R.z;                                                 \
    fs[3] = (P.w + Q.w) + R.w;                                                 \
    /* tanh -> producer-side truncation split -> b16 stores (rows 4q+m) */     \
    _Pragma("unroll")                                                          \
    for (int m = 0; m < 4; ++m){                                               \
      float f = fast_tanh(fs[m]);                                              \
      unsigned u = __float_as_uint(f);                                         \
      (WP)[m*RS_EL] = (unsigned short)(u >> 16);                               \
      float l = f - __uint_as_float(u & 0xffff0000u);                          \
      (WP)[m*RS_EL + LO_EL] = (unsigned short)(__float_as_uint(l) >> 16);      \
    }                                                                          \
    LDS_BARRIER();                                                             \
    /* reload FULL h(t+1) as A-frags: lane (c,q) reads h[c][kt*32+q*8..+7] */  \
    h_hi[0] = (RP)[0];                                                         \
    h_hi[1] = (RP)[4];                                                         \
    h_lo[0] = (RP)[LO_FR];                                                     \
    h_lo[1] = (RP)[LO_FR + 4];                                                 \
  }

__global__ __launch_bounds__(256, 2) void rnn_fused(
    const float* __restrict__ x,
    const float* __restrict__ W_ih,
    const float* __restrict__ W_hh,
    const float* __restrict__ b_ih,
    const float* __restrict__ b_hh,
    const float* __restrict__ W_out,
    const float* __restrict__ b_out,
    float* __restrict__ out)
{
  __shared__ bfrag hsv[2 * BUF_FR];            // 9216 B, double-buffered bf16 h
  const int tid  = threadIdx.x;
  const int w    = tid >> 6;           // wave id = hidden col tile
  const int lane = tid & 63;
  const int c    = lane & 15;
  const int q    = lane >> 4;
  const bool qlt3 = (q < 3);
  const int rowbase = blockIdx.x * ROWS;

  // ---- this wave's W_hh^T B-fragments (hi/lo): cols c+16w, k=32kt+8q+jj ----
  bfrag whh_hi[2], whh_lo[2];
#pragma unroll
  for (int kt = 0; kt < 2; ++kt){
    const float* p = W_hh + (c + 16*w)*H_DIM + kt*32 + q*8;
    split8v(*(const float4v*)p, *(const float4v*)(p + 4), whh_hi[kt], whh_lo[kt]);
  }

  // ---- this wave's W_ih^T B-fragment, K padded 28 -> 32 with zeros ----
  bfrag wih_hi, wih_lo;
  {
    const float* p = W_ih + (c + 16*w)*I_DIM + q*8;
    float4v a = *(const float4v*)p;                        // i <= 27: in-bounds
    float4v b;
    if (qlt3) b = *(const float4v*)(p + 4);
    else      b = (float4v){0.f, 0.f, 0.f, 0.f};           // i = 28..31 pad
    split8v(a, b, wih_hi, wih_lo);
  }

  // bias as C operand; const-zero C for the second chain
  ffrag biasf;
  {
    float bb = b_ih[c + 16*w] + b_hh[c + 16*w];
    biasf.x = bb; biasf.y = bb; biasf.z = bb; biasf.w = bb;
  }
  const ffrag zfrag = {0.f, 0.f, 0.f, 0.f};

  // h fragments (full h as A operand), h0 = 0
  bfrag h_hi[2], h_lo[2];
  {
    FragU Z; Z.u[0]=Z.u[1]=Z.u[2]=Z.u[3]=0;
    h_hi[0] = Z.s; h_lo[0] = Z.s; h_hi[1] = Z.s; h_lo[1] = Z.s;
  }

  // LDS addressing, all precomputed (ds offsets become immediates):
  // producer writes row=4q+m, col=c+16w; consumer reads row=c, k=32kt+8q+jj.
  unsigned short* const wbase = (unsigned short*)hsv;
  unsigned short* const wp0 = wbase + 0*BUF_EL + (4*q)*RS_EL + (c + 16*w);
  unsigned short* const wp1 = wbase + 1*BUF_EL + (4*q)*RS_EL + (c + 16*w);
  const bfrag* const rp0 = hsv + 0*BUF_FR + 9*c + q;
  const bfrag* const rp1 = hsv + 1*BUF_FR + 9*c + q;

  // ---- 4-slot x pipeline (all 4 waves load the same rows; L1 dedupes).
  // Block computes 16 rows rowbase..rowbase+15 (rows >= ROWS duplicate the
  // next block's work bit-identically and are not written). Tail block clamps
  // its x-row to B-1 (valid data; result discarded by the write guard).
  int xr = rowbase + c;
  {
    const int lim = (int)gridDim.x * ROWS - 1;   // B-1
    if (xr > lim) xr = lim;
  }
  const float* xpa = x + ((size_t)xr * T_STEPS) * I_DIM + q*8;
  const float* xpb = qlt3 ? xpa + 4 : xpa;
  float4v xa[4], xb[4];
#pragma unroll
  for (int s = 0; s < 4; ++s){
    xa[s] = *(const float4v*)(xpa + s * I_DIM);
    xb[s] = *(const float4v*)(xpb + s * I_DIM);
  }

  // main: 127 groups with prefetch (last prefetches t=508..511), then a
  // prefetch-free tail group. Even t writes buffer 1, odd t buffer 0.
#pragma unroll 1
  for (int tb = 0; tb < T_STEPS - 4; tb += 4){
    BODY(0, wp1, rp1, 1)
    BODY(1, wp0, rp0, 1)
    BODY(2, wp1, rp1, 1)
    BODY(3, wp0, rp0, 1)
    xpa += 4 * I_DIM;
    xpb += 4 * I_DIM;
  }
  BODY(0, wp1, rp1, 0)
  BODY(1, wp0, rp0, 0)
  BODY(2, wp1, rp1, 0)
  BODY(3, wp0, rp0, 0)

  // epilogue: h_512 is in buffer 0 (t=511 wrote BUF_OFF=0); wave 0 computes
  // out[r][o] = b_out[o] + sum_k h[r][k] * W_out[o][k] for the ROWS owned
  // rows only (r = c < ROWS), o strided by q.
  if (w == 0 && c < ROWS){
    const unsigned short* hb = (const unsigned short*)hsv;   // buffer 0
    for (int oo = q; oo < O_DIM; oo += 4){
      float s = b_out[oo];
#pragma unroll 8
      for (int k = 0; k < H_DIM; ++k){
        float hv = __uint_as_float((unsigned)hb[c*RS_EL + k] << 16)
                 + __uint_as_float((unsigned)hb[c*RS_EL + k + LO_EL] << 16);
        s += hv * W_out[oo*H_DIM + k];
      }
      out[(size_t)(rowbase + c)*O_DIM + oo] = s;
    }
  }
}

extern "C" void kernel_launch(void* const* d_in, const int* in_sizes, int n_in,
                              void* d_out, int out_size, void* d_ws, size_t ws_size,
                              hipStream_t stream) {
  const float* x     = (const float*)d_in[0];
  const float* W_ih  = (const float*)d_in[1];
  const float* W_hh  = (const float*)d_in[2];
  const float* b_ih  = (const float*)d_in[3];
  const float* b_hh  = (const float*)d_in[4];
  const float* W_out = (const float*)d_in[5];
  const float* b_out = (const float*)d_in[6];
  float* out = (float*)d_out;

  int B = in_sizes[0] / (T_STEPS * I_DIM);   // 4096
  rnn_fused<<<B / ROWS, 256, 0, stream>>>(x, W_ih, W_hh, b_ih, b_hh, W_out, b_out, out);
}

// Round 5
// 395.804 us; speedup vs baseline: 1.3068x; 1.2457x over previous
//
#include <hip/hip_runtime.h>

// Fused tanh-RNN: h_{t+1} = tanh(x_t @ W_ih^T + b_ih + b_hh + h_t @ W_hh^T)
// out = h_T @ W_out^T + b_out.  B=4096, T=512, I=28, H=64, O=10.
//
// R9: PRODUCER/CONSUMER WAVE SPECIALIZATION. R8 proved 2 waves/SIMD fill the
// latency gaps (per-block-step 1019->670cy effective) but paid 2x volume via
// duplicated tiles -> net loss. Here the second wave per SIMD does USEFUL
// work instead: block = 512 threads; waves 0-3 = R5's verified column-split
// consumers (h-exchange untouched); waves 4-7 = x-producers. Producer p
// handles steps t==p (mod 4): loads x, runs split8v (the 24-VALU bf16 hi/lo
// split), writes ready A-frags into an 8-slot LDS ring (slot = t%8, 2 groups
// deep). Consumers replace split8v+global-loads+addressing (~110cy/step of
// their ~480cy issue) with 2 ds_read_b128 issued ONE STEP EARLY (latency
// hidden behind the barrier they already pay). Producers run 2 groups ahead
// on register-pinned loads (lead ~2000cy >> 900cy HBM latency) and idle at
// barriers, filling consumer gaps on their shared SIMD.
// Barrier count: exactly 513 per wave in both roles (prologue + 512 steps).
// Arithmetic bit-identical to R5 (same split8v on same x, same MFMA order,
// same h-exchange): absmax 0.00390625.
//
// LDS: h double-buffer 9216B (R5 layout, row stride 144B, conflict-free) +
// x-ring XHI/XLO 8 slots x 64 lanes x 16B = 2 x 8KB (16B/lane contiguous:
// conflict-free b128 both sides). Total 25.6KB, 1 block/CU, grid 256.

#define T_STEPS 512
#define I_DIM   28
#define H_DIM   64
#define O_DIM   10
#define ROWS    16

#define RS_EL   72            // h row stride, bf16 elements (64 + 8 pad)
#define LO_EL   1152          // 16*72: lo-array offset, elements
#define LO_FR   144           // same, in bfrag(16B) units
#define BUF_EL  2304          // elements per h buffer (hi+lo)
#define BUF_FR  288
#define XSLOT_FR 64           // frags per x-ring slot (one per lane)

typedef __attribute__((ext_vector_type(8))) short bfrag;   // 8 x bf16 (4 VGPRs)
typedef __attribute__((ext_vector_type(4))) float ffrag;   // MFMA C/D
typedef __attribute__((ext_vector_type(4))) float float4v;

#define MFMA(a,b,c) __builtin_amdgcn_mfma_f32_16x16x32_bf16((a),(b),(c),0,0,0)
// Workgroup barrier draining ONLY LDS ops (lgkmcnt); global loads (vmcnt)
// stay in flight across it. All 8 waves execute exactly 513 of these.
#define LDS_BARRIER() asm volatile("s_waitcnt lgkmcnt(0)\n\ts_barrier" ::: "memory")

union FragU { bfrag s; unsigned u[4]; };

// pack bf16(f0) | bf16(f1)<<16 in one v_perm_b32 (truncation split)
__device__ __forceinline__ unsigned hi_pack(float f0, float f1){
  return __builtin_amdgcn_perm(__float_as_uint(f1), __float_as_uint(f0), 0x07060302u);
}

// fp32 -> (hi bf16, lo bf16), v = hi + lo up to ~2^-16 rel  (verbatim R5)
__device__ __forceinline__ void split8v(float4v a, float4v b, bfrag& hi, bfrag& lo){
  float f[8] = {a.x,a.y,a.z,a.w, b.x,b.y,b.z,b.w};
  FragU H, L;
#pragma unroll
  for (int m = 0; m < 4; m++){
    float f0 = f[2*m], f1 = f[2*m+1];
    H.u[m] = hi_pack(f0, f1);
    float l0 = f0 - __uint_as_float(__float_as_uint(f0) & 0xffff0000u);
    float l1 = f1 - __uint_as_float(__float_as_uint(f1) & 0xffff0000u);
    L.u[m] = hi_pack(l0, l1);
  }
  hi = H.s; lo = L.s;
}

__device__ __forceinline__ float fast_tanh(float p){
  // tanh(p) = 1 - 2/(exp2(2*log2e*p)+1); saturates correctly for large |p|.
  float e = __builtin_amdgcn_exp2f(p * 2.88539008177792681f);
  return __builtin_fmaf(-2.0f, __builtin_amdgcn_rcpf(e + 1.0f), 1.0f);
}

// Consumer step. Consumes prefetched x-frags (nxh/nxl), computes, stores h,
// prefetches NEXT step's x-frags from ring slot NS, barriers, reloads h.
#define BODY_C(WP, RP, NS)                                                     \
  {                                                                            \
    bfrag xhi = nxh, xlo = nxl;                                                \
    ffrag P, Q, R;                                                             \
    /* x projection heads the chains (frags produced >=1 group early) */       \
    P = MFMA(xhi, wih_hi, biasf);                                              \
    Q = MFMA(xhi, wih_lo, zfrag);                                              \
    P = MFMA(xlo, wih_hi, P);                                                  \
    /* h recurrence: 3 chains, depth 2 from h-ready */                         \
    P = MFMA(h_hi[0], whh_hi[0], P);                                           \
    Q = MFMA(h_hi[1], whh_hi[1], Q);                                           \
    R = MFMA(h_hi[0], whh_lo[0], zfrag);                                       \
    P = MFMA(h_lo[0], whh_hi[0], P);                                           \
    Q = MFMA(h_lo[1], whh_hi[1], Q);                                           \
    R = MFMA(h_hi[1], whh_lo[1], R);                                           \
    float fs[4];                                                               \
    fs[0] = (P.x + Q.x) + R.x;                                                 \
    fs[1] = (P.y + Q.y) + R.y;                                                 \
    fs[2] = (P.z + Q.z) + R.z;                                                 \
    fs[3] = (P.w + Q.w) + R.w;                                                 \
    /* tanh -> producer-side truncation split -> b16 stores (rows 4q+m) */     \
    _Pragma("unroll")                                                          \
    for (int m = 0; m < 4; ++m){                                               \
      float f = fast_tanh(fs[m]);                                              \
      unsigned u = __float_as_uint(f);                                         \
      (WP)[m*RS_EL] = (unsigned short)(u >> 16);                               \
      float l = f - __uint_as_float(u & 0xffff0000u);                          \
      (WP)[m*RS_EL + LO_EL] = (unsigned short)(__float_as_uint(l) >> 16);      \
    }                                                                          \
    /* prefetch next step's x-frags (written >=3 barriers ago) */              \
    nxh = xrh[(NS) * XSLOT_FR];                                                \
    nxl = xrl[(NS) * XSLOT_FR];                                                \
    LDS_BARRIER();                                                             \
    /* reload FULL h(t+1) as A-frags: lane (c,q) reads h[c][kt*32+q*8..+7] */  \
    h_hi[0] = (RP)[0];                                                         \
    h_hi[1] = (RP)[4];                                                         \
    h_lo[0] = (RP)[LO_FR];                                                     \
    h_lo[1] = (RP)[LO_FR + 4];                                                 \
  }

// Producer: split regs (A or B) into frags, write ring slot S (uniform imm).
#define PRODUCE(AR, BR, S)                                                     \
  {                                                                            \
    bfrag fh, fl;                                                              \
    split8v(AR, BR, fh, fl);                                                   \
    xwh[(S) * XSLOT_FR] = fh;                                                  \
    xwl[(S) * XSLOT_FR] = fl;                                                  \
  }

__global__ __launch_bounds__(512, 1) void rnn_fused(
    const float* __restrict__ x,
    const float* __restrict__ W_ih,
    const float* __restrict__ W_hh,
    const float* __restrict__ b_ih,
    const float* __restrict__ b_hh,
    const float* __restrict__ W_out,
    const float* __restrict__ b_out,
    float* __restrict__ out)
{
  __shared__ bfrag hsv[2 * BUF_FR];        // 9216 B h double-buffer
  __shared__ bfrag xhi_s[8 * XSLOT_FR];    // 8 KB x-ring (hi frags)
  __shared__ bfrag xlo_s[8 * XSLOT_FR];    // 8 KB x-ring (lo frags)
  const int tid  = threadIdx.x;
  const int w    = tid >> 6;           // 0-3 consumers (col tile), 4-7 producers
  const int lane = tid & 63;
  const int c    = lane & 15;
  const int q    = lane >> 4;
  const bool qlt3 = (q < 3);
  const int rowbase = blockIdx.x * ROWS;

  if (w < 4){
    // ================= CONSUMER (identical compute core to R5) =============
    bfrag whh_hi[2], whh_lo[2];
#pragma unroll
    for (int kt = 0; kt < 2; ++kt){
      const float* p = W_hh + (c + 16*w)*H_DIM + kt*32 + q*8;
      split8v(*(const float4v*)p, *(const float4v*)(p + 4), whh_hi[kt], whh_lo[kt]);
    }

    bfrag wih_hi, wih_lo;
    {
      const float* p = W_ih + (c + 16*w)*I_DIM + q*8;
      float4v a = *(const float4v*)p;                      // i <= 27: in-bounds
      float4v b;
      if (qlt3) b = *(const float4v*)(p + 4);
      else      b = (float4v){0.f, 0.f, 0.f, 0.f};         // i = 28..31 pad
      split8v(a, b, wih_hi, wih_lo);
    }

    ffrag biasf;
    {
      float bb = b_ih[c + 16*w] + b_hh[c + 16*w];
      biasf.x = bb; biasf.y = bb; biasf.z = bb; biasf.w = bb;
    }
    const ffrag zfrag = {0.f, 0.f, 0.f, 0.f};

    bfrag h_hi[2], h_lo[2];
    {
      FragU Z; Z.u[0]=Z.u[1]=Z.u[2]=Z.u[3]=0;
      h_hi[0] = Z.s; h_lo[0] = Z.s; h_hi[1] = Z.s; h_lo[1] = Z.s;
    }

    unsigned short* const wbase = (unsigned short*)hsv;
    unsigned short* const wp0 = wbase + 0*BUF_EL + (4*q)*RS_EL + (c + 16*w);
    unsigned short* const wp1 = wbase + 1*BUF_EL + (4*q)*RS_EL + (c + 16*w);
    const bfrag* const rp0 = hsv + 0*BUF_FR + 9*c + q;
    const bfrag* const rp1 = hsv + 1*BUF_FR + 9*c + q;
    const bfrag* const xrh = xhi_s + lane;
    const bfrag* const xrl = xlo_s + lane;

    LDS_BARRIER();                               // prologue (ring slot 0 ready)
    bfrag nxh = xrh[0], nxl = xrl[0];            // t=0 frags

    // 63 double-groups (8 steps each; slots 0..7, h-buffers alternate 1,0)
#pragma unroll 1
    for (int j = 0; j < 63; ++j){
      BODY_C(wp1, rp1, 1)
      BODY_C(wp0, rp0, 2)
      BODY_C(wp1, rp1, 3)
      BODY_C(wp0, rp0, 4)
      BODY_C(wp1, rp1, 5)
      BODY_C(wp0, rp0, 6)
      BODY_C(wp1, rp1, 7)
      BODY_C(wp0, rp0, 0)
    }
    // groups 126 (slots 0-3) and 127 (slots 4-7): t=504..511
    BODY_C(wp1, rp1, 1)
    BODY_C(wp0, rp0, 2)
    BODY_C(wp1, rp1, 3)
    BODY_C(wp0, rp0, 4)
    BODY_C(wp1, rp1, 5)
    BODY_C(wp0, rp0, 6)
    BODY_C(wp1, rp1, 7)
    BODY_C(wp0, rp0, 0)        // t=511 writes buffer 0; final prefetch harmless

    // epilogue: h_512 in buffer 0; wave 0 computes the O=10 projection.
    if (w == 0){
      const unsigned short* hb = (const unsigned short*)hsv;   // buffer 0
      for (int oo = q; oo < O_DIM; oo += 4){
        float s = b_out[oo];
#pragma unroll 8
        for (int k = 0; k < H_DIM; ++k){
          float hv = __uint_as_float((unsigned)hb[c*RS_EL + k] << 16)
                   + __uint_as_float((unsigned)hb[c*RS_EL + k + LO_EL] << 16);
          s += hv * W_out[oo*H_DIM + k];
        }
        out[(size_t)(rowbase + c)*O_DIM + oo] = s;
      }
    }
  } else {
    // ================= PRODUCER (wave p handles t == p mod 4) ==============
    const int p = w - 4;
    const float* xpa = x + ((size_t)(rowbase + c) * T_STEPS) * I_DIM + q*8;
    const float* xpb = qlt3 ? xpa + 4 : xpa;     // q=3 upper half hits W pad
    bfrag* const xwh = xhi_s + lane;
    bfrag* const xwl = xlo_s + lane;

    // group-0 (t=p) + 2-group register pipeline (A: odd groups, B: even)
    float4v a0 = *(const float4v*)(xpa + p*I_DIM);
    float4v b0 = *(const float4v*)(xpb + p*I_DIM);
    float4v aA = *(const float4v*)(xpa + (4+p)*I_DIM);   // group 1
    float4v bA = *(const float4v*)(xpb + (4+p)*I_DIM);
    float4v aB = *(const float4v*)(xpa + (8+p)*I_DIM);   // group 2
    float4v bB = *(const float4v*)(xpb + (8+p)*I_DIM);
    PRODUCE(a0, b0, p)                           // slot p = t%8 for t=p
    LDS_BARRIER();                               // prologue

    const float* la = xpa + (size_t)(12+p)*I_DIM;   // next A-load: group 3
    const float* lb = xpb + (size_t)(12+p)*I_DIM;
#pragma unroll 1
    for (int j = 0; j < 63; ++j){
      // produce group 2j+1 (t=8j+4+p -> slot 4+p); reload A <- group 2j+3
      PRODUCE(aA, bA, 4 + p)
      aA = *(const float4v*)la;                  // t = 8j+12+p  (<=508+p)
      bA = *(const float4v*)lb;
      LDS_BARRIER(); LDS_BARRIER(); LDS_BARRIER(); LDS_BARRIER();
      // produce group 2j+2 (t=8j+8+p -> slot p); reload B <- group 2j+4
      PRODUCE(aB, bB, p)
      {
        // t = 8j+16+p; at j=62 that is OOB -> re-load A's address (dead value)
        const float* ca = (j < 62) ? la + 4*I_DIM : la;
        const float* cb = (j < 62) ? lb + 4*I_DIM : lb;
        aB = *(const float4v*)ca;
        bB = *(const float4v*)cb;
      }
      la += 8*I_DIM; lb += 8*I_DIM;
      LDS_BARRIER(); LDS_BARRIER(); LDS_BARRIER(); LDS_BARRIER();
    }
    // group 127 (t=508+p, in A since j=62's reload) -> slots 4..7
    PRODUCE(aA, bA, 4 + p)
    LDS_BARRIER(); LDS_BARRIER(); LDS_BARRIER(); LDS_BARRIER();  // group 126
    LDS_BARRIER(); LDS_BARRIER(); LDS_BARRIER(); LDS_BARRIER();  // group 127
  }
}

extern "C" void kernel_launch(void* const* d_in, const int* in_sizes, int n_in,
                              void* d_out, int out_size, void* d_ws, size_t ws_size,
                              hipStream_t stream) {
  const float* x     = (const float*)d_in[0];
  const float* W_ih  = (const float*)d_in[1];
  const float* W_hh  = (const float*)d_in[2];
  const float* b_ih  = (const float*)d_in[3];
  const float* b_hh  = (const float*)d_in[4];
  const float* W_out = (const float*)d_in[5];
  const float* b_out = (const float*)d_in[6];
  float* out = (float*)d_out;

  int B = in_sizes[0] / (T_STEPS * I_DIM);   // 4096
  rnn_fused<<<B / ROWS, 512, 0, stream>>>(x, W_ih, W_hh, b_ih, b_hh, W_out, b_out, out);
}